// Round 16
// baseline (2713.616 us; speedup 1.0000x reference)
//
#include <hip/hip_runtime.h>
#include <hip/hip_bf16.h>
#include <math.h>

// HAN: word bi-GRU + attention -> sentence bi-GRU + attention -> doc vector.
// R16: word_rnn: full-breadth load issue (all 16 hb loads in flight/lane ->
// miss phase collapses to ~1 latency), hpk -> normal cached stores (only the
// producing block rereads it in-loop; coherence via dispatch boundary for
// attention), psum stride 19 (bank-conflict-free), faster spin wake.

typedef __attribute__((ext_vector_type(8))) short short8;
typedef __attribute__((ext_vector_type(4))) float f32x4;
typedef __attribute__((ext_vector_type(4))) unsigned u32x4;

__device__ __forceinline__ unsigned short f2bf(float f) {
    unsigned int u = __float_as_uint(f);
    u += 0x7fff + ((u >> 16) & 1);   // RNE
    return (unsigned short)(u >> 16);
}
__device__ __forceinline__ float bf2f(unsigned short u) {
    return __uint_as_float(((unsigned int)u) << 16);
}
__device__ __forceinline__ float unpk2f(unsigned p) {   // hi in low16, lo in high16
    return __uint_as_float(p << 16) + __uint_as_float(p & 0xffff0000u);
}
__device__ __forceinline__ float sigmoidf_(float x) { return 1.f / (1.f + expf(-x)); }

__device__ __forceinline__ f32x4 mfma16(short8 a, short8 b, f32x4 c) {
    return __builtin_amdgcn_mfma_f32_16x16x32_bf16(a, b, c, 0, 0, 0);
}

// coherent (IF-direct) u32 store, relaxed
__device__ __forceinline__ void st_coh_u(unsigned* p, unsigned v) {
    __hip_atomic_store(p, v, __ATOMIC_RELAXED, __HIP_MEMORY_SCOPE_AGENT);
}
__device__ __forceinline__ void st_coh_f(float* p, float v) {
    __hip_atomic_store((unsigned*)p, __float_as_uint(v),
                       __ATOMIC_RELAXED, __HIP_MEMORY_SCOPE_AGENT);
}

// Tree barrier for a 128-block domain (8 groups of 16). Monotonic counters,
// all relaxed, no cache maintenance.
__device__ __forceinline__ void gbar_tree(unsigned* base, unsigned tau, int dblk) {
    asm volatile("s_waitcnt vmcnt(0)" ::: "memory");   // drain coherent stores
    __syncthreads();
    if (threadIdx.x == 0) {
        int g = dblk >> 4;
        unsigned* gcnt = base + g * 16;
        unsigned* root = base + 128;
        unsigned* flag = base + 144 + g * 16;
        unsigned old = __hip_atomic_fetch_add(gcnt, 1u, __ATOMIC_RELAXED, __HIP_MEMORY_SCOPE_AGENT);
        if ((old & 15u) == 15u)
            __hip_atomic_fetch_add(root, 1u, __ATOMIC_RELAXED, __HIP_MEMORY_SCOPE_AGENT);
        if ((dblk & 15) == 0) {
            unsigned target = 8u * (tau + 1u);
            while (__hip_atomic_load(root, __ATOMIC_RELAXED, __HIP_MEMORY_SCOPE_AGENT) < target)
                __builtin_amdgcn_s_sleep(1);
            __hip_atomic_store(flag, tau + 1u, __ATOMIC_RELAXED, __HIP_MEMORY_SCOPE_AGENT);
        } else {
            while (__hip_atomic_load(flag, __ATOMIC_RELAXED, __HIP_MEMORY_SCOPE_AGENT) < tau + 1u)
                __builtin_amdgcn_s_sleep(1);
        }
    }
    __syncthreads();
    asm volatile("" ::: "memory");
}

// ---------------- split f32 -> (hi,lo) bf16 ----------------
__global__ __launch_bounds__(256) void split_f32(const float* __restrict__ src,
                                                 unsigned short* __restrict__ hi,
                                                 unsigned short* __restrict__ lo, int n) {
    int i = blockIdx.x * blockDim.x + threadIdx.x;
    int stride = gridDim.x * blockDim.x;
    for (; i < n; i += stride) {
        float v = src[i];
        unsigned short h = f2bf(v);
        hi[i] = h;
        lo[i] = f2bf(v - bf2f(h));
    }
}

// ---------------- split-bf16 MFMA GEMM (NT), XCD-chunked 1D grid ------------
__global__ __launch_bounds__(256) void gemm_split(
    const float* __restrict__ A, const int* __restrict__ tokens,
    const unsigned short* __restrict__ Bhi, const unsigned short* __restrict__ Blo,
    const float* __restrict__ bias, float* __restrict__ C,
    int M, int N, int K, int tr96)
{
    __shared__ unsigned short Ah[64][40], Al[64][40];
    __shared__ unsigned short Bh[128][40], Bl[128][40];

    int t = threadIdx.x;
    int nt = N >> 7;
    int mt = gridDim.x / nt;
    int nchunk = nt >> 3;
    int b = blockIdx.x;
    int xcd = b & 7, bi_ = b >> 3;
    int m0 = (bi_ % mt) * 64;
    int n0 = (xcd * nchunk + bi_ / mt) * 128;

    int wave = t >> 6, lane = t & 63;
    int wm = wave >> 1, wn = wave & 1;
    int kg = lane >> 4, r16 = lane & 15;

    f32x4 acc[2][4];
#pragma unroll
    for (int i = 0; i < 2; i++)
#pragma unroll
        for (int j = 0; j < 4; j++)
#pragma unroll
            for (int q = 0; q < 4; q++) acc[i][j][q] = 0.f;

    int ar = t >> 2, ac8 = (t & 3) * 8;
    long arow = -1;
    if (m0 + ar < M) arow = tokens ? (long)tokens[m0 + ar] : (long)(m0 + ar);

    for (int kt = 0; kt < K; kt += 32) {
        {
            short8 hv, lv;
            if (arow >= 0) {
                const float* ap = A + arow * (long)K + kt + ac8;
                f32x4 u0 = *(const f32x4*)ap;
                f32x4 u1 = *(const f32x4*)(ap + 4);
#pragma unroll
                for (int i = 0; i < 8; i++) {
                    float x = (i < 4) ? u0[i] : u1[i - 4];
                    unsigned short hb = f2bf(x);
                    hv[i] = (short)hb;
                    lv[i] = (short)f2bf(x - bf2f(hb));
                }
            } else {
#pragma unroll
                for (int i = 0; i < 8; i++) { hv[i] = 0; lv[i] = 0; }
            }
            *(short8*)&Ah[ar][ac8] = hv;
            *(short8*)&Al[ar][ac8] = lv;
        }
#pragma unroll
        for (int i = 0; i < 2; i++) {
            int idx = t + i * 256;
            int br = idx >> 2, bc8 = (idx & 3) * 8;
            long go = (long)(n0 + br) * K + kt + bc8;
            *(short8*)&Bh[br][bc8] = *(const short8*)(Bhi + go);
            *(short8*)&Bl[br][bc8] = *(const short8*)(Blo + go);
        }
        __syncthreads();

        short8 afh[2], afl[2], bfh[4], bfl[4];
#pragma unroll
        for (int m16 = 0; m16 < 2; m16++) {
            afh[m16] = *(short8*)&Ah[wm * 32 + m16 * 16 + r16][kg * 8];
            afl[m16] = *(short8*)&Al[wm * 32 + m16 * 16 + r16][kg * 8];
        }
#pragma unroll
        for (int n16 = 0; n16 < 4; n16++) {
            bfh[n16] = *(short8*)&Bh[wn * 64 + n16 * 16 + r16][kg * 8];
            bfl[n16] = *(short8*)&Bl[wn * 64 + n16 * 16 + r16][kg * 8];
        }
#pragma unroll
        for (int m16 = 0; m16 < 2; m16++)
#pragma unroll
            for (int n16 = 0; n16 < 4; n16++) {
                acc[m16][n16] = mfma16(afh[m16], bfh[n16], acc[m16][n16]);
                acc[m16][n16] = mfma16(afh[m16], bfl[n16], acc[m16][n16]);
                acc[m16][n16] = mfma16(afl[m16], bfh[n16], acc[m16][n16]);
            }
        __syncthreads();
    }

#pragma unroll
    for (int m16 = 0; m16 < 2; m16++)
#pragma unroll
        for (int n16 = 0; n16 < 4; n16++)
#pragma unroll
            for (int q = 0; q < 4; q++) {
                int row = m0 + wm * 32 + m16 * 16 + kg * 4 + q;
                int col = n0 + wn * 64 + n16 * 16 + r16;
                if (row < M) {
                    long crow = tr96 ? (long)((row % 96) * 96 + row / 96) : (long)row;
                    C[crow * N + col] = acc[m16][n16][q] + bias[col];
                }
            }
}

// ---------------- persistent word bi-GRU v12 (full-breadth loads) -----------
// 256 blocks x 768 thr (12 waves = 3 m-tiles(M-rep2) x 4 K-quarters).
// All 16 hb loads issued up front per wave; hpk stored with normal cached
// stores (same-block reread only); hb stays coherent (cross-XCD).
__global__ __launch_bounds__(768) void word_rnn(
    const unsigned short* __restrict__ Whi, const unsigned short* __restrict__ Wlo,
    const float* __restrict__ xWt,   // [96 pos][96 s][3072]
    const float* __restrict__ bhh, unsigned* __restrict__ hpk,
    unsigned short* __restrict__ hb, unsigned* barbase)
{
    __shared__ unsigned short Wh[2][128][25][8];    // 102.4 KB
    __shared__ float psum[3][3][64 * 19];           // 43.7 KB, stride 19

    int t = threadIdx.x;
    int blk = blockIdx.x;
    int msplit = blk >> 7;
    int dblk = blk & 127;
    unsigned* dom = barbase + msplit * 512;
    // XCD-contiguous j-panel: XCD c (blk%8) owns j [c*128, c*128+128)
    int j0 = (((dblk & 7) << 4) + (dblk >> 3)) << 3;
    int wv = t >> 6;                  // 0..11
    int w3 = wv % 3, kq = wv / 3;     // m-tile (32 rows), K-quarter (0..3)
    int lane = t & 63, kg4 = lane >> 4, r16 = lane & 15;
    int wstart = blk & 7;             // per-block window rotation (8 windows)

    for (int i = t; i < 4096; i += 768) {
        int kg = i >> 5, br = i & 31;
        if (br < 24) {
            long src = (long)((br >> 3) * 1024 + j0 + (br & 7)) * 1024 + kg * 8;
            *(short8*)&Wh[0][kg][br][0] = *(const short8*)(Whi + src);
            *(short8*)&Wh[1][kg][br][0] = *(const short8*)(Wlo + src);
        }
    }
    __syncthreads();

    int jj = r16 & 7;
    int j = j0 + jj;
    float b_r = bhh[j], b_z = bhh[1024 + j], b_n = bhh[2048 + j];
    int sf0 = w3 * 32 + r16;          // row rep 0 (rep 1 = +16)
    const long ROWSTRIDE = (long)16 * 96 * 2048;   // 16 sentences

    short8 X0, X1, X2, X3, X4, X5, X6, X7;
    short8 Y0, Y1, Y2, Y3, Y4, Y5, Y6, Y7;

#define KOFF(i) (kq * 8 + ((wstart + (i)) & 7))

#define LDW2(s, i)                                                        \
    do {                                                                  \
        X##s = *(const short8*)(ab0 + KOFF(i) * 32);                      \
        Y##s = *(const short8*)(ab1 + KOFF(i) * 32);                      \
    } while (0)

#define DOW2(s, i)                                                        \
    do {                                                                  \
        int kgB = KOFF(i) * 4 + kg4;                                      \
        short8 b0h = *(short8*)&Wh[0][kgB][r16][0];                       \
        short8 b0l = *(short8*)&Wh[1][kgB][r16][0];                       \
        short8 b1h = *(short8*)&Wh[0][kgB][16 + jj][0];                   \
        short8 b1l = *(short8*)&Wh[1][kgB][16 + jj][0];                   \
        acc00 = mfma16(X##s, b0h, acc00);                                 \
        acc10 = mfma16(Y##s, b0h, acc10);                                 \
        acc00 = mfma16(X##s, b0l, acc00);                                 \
        acc10 = mfma16(Y##s, b0l, acc10);                                 \
        acc01 = mfma16(X##s, b1h, acc01);                                 \
        acc11 = mfma16(Y##s, b1h, acc11);                                 \
        acc01 = mfma16(X##s, b1l, acc01);                                 \
        acc11 = mfma16(Y##s, b1l, acc11);                                 \
    } while (0)

    for (int tau = 0; tau < 96; tau++) {
        int pos  = msplit ? (95 - tau) : tau;
        int posp = msplit ? (96 - tau) : (tau - 1);

        const unsigned short* ab0 = hb + ((long)sf0 * 96 + posp) * 2048 + msplit * 1024 + kg4 * 8;
        const unsigned short* ab1 = ab0 + ROWSTRIDE;

        f32x4 acc00, acc01, acc10, acc11;
#pragma unroll
        for (int q = 0; q < 4; q++) { acc00[q] = 0.f; acc01[q] = 0.f; acc10[q] = 0.f; acc11[q] = 0.f; }

        if (tau > 0) {
            // full-breadth issue: all 16 loads in flight before any compute
            LDW2(0, 0); LDW2(1, 1); LDW2(2, 2); LDW2(3, 3);
            LDW2(4, 4); LDW2(5, 5); LDW2(6, 6); LDW2(7, 7);
        }

        // epilogue operands (kq==0 producing lanes), retire under K-loop
        float xwv[2][4][3];
        float hpv[2][4];
#pragma unroll
        for (int mi = 0; mi < 2; mi++)
#pragma unroll
            for (int q = 0; q < 4; q++) {
                if (kq == 0 && r16 < 8) {
                    int hloc = w3 * 32 + mi * 16 + kg4 * 4 + q;
                    const float* xp = xWt + ((long)pos * 96 + hloc) * 3072 + j;
                    xwv[mi][q][0] = xp[0];
                    xwv[mi][q][1] = xp[1024];
                    xwv[mi][q][2] = xp[2048];
                    hpv[mi][q] = (tau > 0)
                        ? unpk2f(hpk[((long)hloc * 96 + posp) * 2048 + msplit * 1024 + j]) : 0.f;
                } else {
                    xwv[mi][q][0] = xwv[mi][q][1] = xwv[mi][q][2] = 0.f;
                    hpv[mi][q] = 0.f;
                }
            }

        if (tau > 0) {
            DOW2(0, 0); DOW2(1, 1); DOW2(2, 2); DOW2(3, 3);
            DOW2(4, 4); DOW2(5, 5); DOW2(6, 6); DOW2(7, 7);
        }

        // K-quarter partial exchange (kq 1..3 write, kq 0 reduces)
        if (kq >= 1) {
            float* ps = &psum[kq - 1][w3][lane * 19];
#pragma unroll
            for (int q = 0; q < 4; q++) {
                ps[q]      = acc00[q];
                ps[4 + q]  = acc01[q];
                ps[8 + q]  = acc10[q];
                ps[12 + q] = acc11[q];
            }
        }
        __syncthreads();

        if (kq == 0) {
#pragma unroll
            for (int mi = 0; mi < 2; mi++) {
#pragma unroll
                for (int q = 0; q < 4; q++) {
                    float a0 = (mi == 0) ? acc00[q] : acc10[q];
                    float a1 = (mi == 0) ? acc01[q] : acc11[q];
                    int o0 = lane * 19 + mi * 8 + q;
                    float g0 = a0 + psum[0][w3][o0] + psum[1][w3][o0] + psum[2][w3][o0];
                    float g2 = a1 + psum[0][w3][o0 + 4] + psum[1][w3][o0 + 4] + psum[2][w3][o0 + 4];
                    float g1 = __shfl_xor(g0, 8);
                    float rr = sigmoidf_(xwv[mi][q][0] + g0 + b_r);
                    float zz = sigmoidf_(xwv[mi][q][1] + g1 + b_z);
                    float nn = tanhf(xwv[mi][q][2] + rr * (g2 + b_n));
                    float hnew = (1.f - zz) * nn + zz * hpv[mi][q];
                    unsigned hbb = f2bf(hnew);
                    unsigned nb = (unsigned)__shfl_xor((int)hbb, 1);
                    if (r16 < 8) {
                        int hloc = w3 * 32 + mi * 16 + kg4 * 4 + q;
                        long base = ((long)hloc * 96 + pos) * 2048 + msplit * 1024 + j;
                        unsigned lb = f2bf(hnew - bf2f((unsigned short)hbb));
                        hpk[base] = hbb | (lb << 16);            // cached store (self-reread)
                        if ((jj & 1) == 0)
                            st_coh_u((unsigned*)hb + (base >> 1), hbb | (nb << 16));
                    }
                }
            }
        }

        if (tau != 95) gbar_tree(dom, tau, dblk);
    }
#undef KOFF
#undef LDW2
#undef DOW2
}

// ---------------- word attention (read exact hpk) ----------------
__global__ __launch_bounds__(256) void wscore(
    const unsigned* __restrict__ hpk, const float* __restrict__ wctx,
    const float* __restrict__ wctx_b, float* __restrict__ wsc)
{
    int tok = blockIdx.x * 4 + (threadIdx.x >> 6);
    int lane = threadIdx.x & 63;
    const unsigned* row = hpk + (long)tok * 2048 + lane * 32;
    const float* cp = wctx + lane * 32;
    float p = 0.f;
#pragma unroll
    for (int i = 0; i < 32; i += 4) {
        u32x4 v = *(const u32x4*)(row + i);
        f32x4 c = *(const f32x4*)(cp + i);
        p += unpk2f(v[0]) * c[0] + unpk2f(v[1]) * c[1]
           + unpk2f(v[2]) * c[2] + unpk2f(v[3]) * c[3];
    }
    p += __shfl_xor(p, 32); p += __shfl_xor(p, 16); p += __shfl_xor(p, 8);
    p += __shfl_xor(p, 4);  p += __shfl_xor(p, 2);  p += __shfl_xor(p, 1);
    if (lane == 0) wsc[tok] = expf(p + wctx_b[0]);
}

__global__ __launch_bounds__(256) void wsum(
    const unsigned* __restrict__ hpk, const float* __restrict__ wsc,
    float* __restrict__ sent_vecs)
{
    int s = blockIdx.x;
    int c = blockIdx.y * 256 + threadIdx.x;
    float acc = 0.f;
    for (int tk = 0; tk < 96; tk++)
        acc += wsc[s * 96 + tk] * unpk2f(hpk[((long)s * 96 + tk) * 2048 + c]);
    sent_vecs[(long)s * 2048 + c] = acc;
}

// ---------------- persistent sentence bi-GRU (tree barrier) ----------------
__global__ __launch_bounds__(256) void sent_rnn(
    const float* __restrict__ sWhh, const float* __restrict__ xWs,
    const float* __restrict__ sbhh, float* __restrict__ sbi,
    unsigned* barbase)
{
    __shared__ float Wl[24 * 1028];
    __shared__ float hsh[2048];
    __shared__ float part[4][48];

    int t = threadIdx.x;
    int j0 = blockIdx.x * 8;
    int w = t >> 6, lane = t & 63;

    for (int i = t; i < 24 * 1024; i += 256) {
        int row = i >> 10, k = i & 1023;
        Wl[row * 1028 + k] = sWhh[(long)((row >> 3) * 1024 + j0 + (row & 7)) * 1024 + k];
    }

    for (int tau = 0; tau < 96; tau++) {
        int posp0 = tau - 1, posp1 = 96 - tau;
        __syncthreads();
        for (int i = t; i < 2048; i += 256) {
            int bq = i >> 10, k = i & 1023;
            int pp = bq ? posp1 : posp0;
            hsh[i] = (tau > 0) ? sbi[(long)pp * 2048 + bq * 1024 + k] : 0.f;
        }
        __syncthreads();

        if (lane < 48) {
            int row = lane >> 1, bq = lane & 1;
            const float* wp = &Wl[row * 1028 + w * 256];
            const float* hp = &hsh[bq * 1024 + w * 256];
            float accd = 0.f;
            for (int k = 0; k < 256; k += 4) {
                f32x4 wv = *(const f32x4*)(wp + k);
                f32x4 hv = *(const f32x4*)(hp + k);
                accd += wv[0] * hv[0] + wv[1] * hv[1] + wv[2] * hv[2] + wv[3] * hv[3];
            }
            part[w][lane] = accd;
        }
        __syncthreads();

        if (t < 16) {
            int jl2 = t >> 1, bq = t & 1;
            int jv = j0 + jl2;
            int pos = bq ? (95 - tau) : tau;
            int pp  = bq ? posp1 : posp0;
            const float* xp = xWs + (long)pos * 3072;
            int d0 = (0 * 8 + jl2) * 2 + bq;
            int d1 = (1 * 8 + jl2) * 2 + bq;
            int d2 = (2 * 8 + jl2) * 2 + bq;
            float D0 = part[0][d0] + part[1][d0] + part[2][d0] + part[3][d0];
            float D1 = part[0][d1] + part[1][d1] + part[2][d1] + part[3][d1];
            float D2 = part[0][d2] + part[1][d2] + part[2][d2] + part[3][d2];
            float rr = sigmoidf_(xp[jv] + D0 + sbhh[jv]);
            float zz = sigmoidf_(xp[1024 + jv] + D1 + sbhh[1024 + jv]);
            float nn = tanhf(xp[2048 + jv] + rr * (D2 + sbhh[2048 + jv]));
            float hprev = (tau > 0) ? sbi[(long)pp * 2048 + bq * 1024 + jv] : 0.f;
            float hnew = (1.f - zz) * nn + zz * hprev;
            st_coh_f(sbi + (long)pos * 2048 + bq * 1024 + jv, hnew);
        }

        if (tau != 95) gbar_tree(barbase, tau, blockIdx.x);
    }
}

// ---------------- sentence attention ----------------
__global__ __launch_bounds__(256) void sent_scores(
    const float* __restrict__ sbi, const float* __restrict__ sctx,
    const float* __restrict__ sctx_b, float* __restrict__ scores)
{
    __shared__ float red[4];
    int s = blockIdx.x, t = threadIdx.x, c = t * 8;
    const float* row = sbi + (long)s * 2048 + c;
    float p = 0.f;
#pragma unroll
    for (int i = 0; i < 8; i++) p += row[i] * sctx[c + i];
    p += __shfl_xor(p, 32); p += __shfl_xor(p, 16); p += __shfl_xor(p, 8);
    p += __shfl_xor(p, 4);  p += __shfl_xor(p, 2);  p += __shfl_xor(p, 1);
    int lane = t & 63, w = t >> 6;
    if (lane == 0) red[w] = p;
    __syncthreads();
    if (t == 0) scores[s] = expf(red[0] + red[1] + red[2] + red[3] + sctx_b[0]);
}

__global__ __launch_bounds__(256) void doc_out(
    const float* __restrict__ sbi, const float* __restrict__ scores,
    float* __restrict__ out)
{
    int t = threadIdx.x, c = t * 8;
    float acc[8];
#pragma unroll
    for (int i = 0; i < 8; i++) acc[i] = 0.f;
    for (int s = 0; s < 96; s++) {
        float sc = scores[s];
        const float* row = sbi + (long)s * 2048 + c;
#pragma unroll
        for (int i = 0; i < 8; i++) acc[i] += sc * row[i];
    }
#pragma unroll
    for (int i = 0; i < 8; i++) out[c + i] = acc[i];
}

// ---------------- host ----------------
extern "C" void kernel_launch(void* const* d_in, const int* in_sizes, int n_in,
                              void* d_out, int out_size, void* d_ws, size_t ws_size,
                              hipStream_t stream)
{
    const int*   tokens    = (const int*)  d_in[0];
    const float* embedding = (const float*)d_in[1];
    const float* wWih = (const float*)d_in[2];
    const float* wWhh = (const float*)d_in[3];
    const float* wbih = (const float*)d_in[4];
    const float* wbhh = (const float*)d_in[5];
    const float* sWih = (const float*)d_in[6];
    const float* sWhh = (const float*)d_in[7];
    const float* sbih = (const float*)d_in[8];
    const float* sbhh = (const float*)d_in[9];
    const float* wctxw = (const float*)d_in[10];
    const float* wctxb = (const float*)d_in[11];
    const float* sctxw = (const float*)d_in[12];
    const float* sctxb = (const float*)d_in[13];
    float* out = (float*)d_out;

    char* p = (char*)d_ws;
    auto alloc = [&](size_t bytes) -> char* {
        char* r = p;
        p += (bytes + 255) & ~(size_t)255;
        return r;
    };
    unsigned short* WihHi  = (unsigned short*)alloc(3072l * 1024 * 2);
    unsigned short* WihLo  = (unsigned short*)alloc(3072l * 1024 * 2);
    unsigned short* WhhHi  = (unsigned short*)alloc(3072l * 1024 * 2);
    unsigned short* WhhLo  = (unsigned short*)alloc(3072l * 1024 * 2);
    unsigned short* sWihHi = (unsigned short*)alloc(3072l * 2048 * 2);
    unsigned short* sWihLo = (unsigned short*)alloc(3072l * 2048 * 2);
    float* xWt       = (float*)alloc(9216l * 3072 * 4);     // [pos][s][3072]
    unsigned* hpk    = (unsigned*)alloc(9216l * 2048 * 4);  // packed exact h / bi
    unsigned short* hb = (unsigned short*)alloc(9216l * 2048 * 2);  // bf16 h
    float* sent_vecs = (float*)alloc(96l * 2048 * 4);
    float* xWs       = (float*)alloc(96l * 3072 * 4);
    float* sbi       = (float*)alloc(96l * 2048 * 4);       // also sent h state
    float* scores    = (float*)alloc(512);
    float* wsc       = (float*)alloc(9216l * 4);
    unsigned* barbuf = (unsigned*)alloc(16384);
    (void)ws_size; (void)in_sizes; (void)n_in; (void)out_size;

    hipMemsetAsync(barbuf, 0, 16384, stream);

    split_f32<<<1024, 256, 0, stream>>>(wWih, WihHi, WihLo, 3072 * 1024);
    split_f32<<<1024, 256, 0, stream>>>(wWhh, WhhHi, WhhLo, 3072 * 1024);
    split_f32<<<1024, 256, 0, stream>>>(sWih, sWihHi, sWihLo, 3072 * 2048);

    // word input projection, stored transposed: xWt[pos][s][3072]
    gemm_split<<<144 * 24, 256, 0, stream>>>(
        embedding, tokens, WihHi, WihLo, wbih, xWt, 9216, 3072, 1024, 1);

    // persistent word bi-GRU (fwd/bwd tree-barrier domains 0,1)
    word_rnn<<<256, 768, 0, stream>>>(
        WhhHi, WhhLo, xWt, wbhh, hpk, hb, barbuf);

    // word attention
    wscore<<<2304, 256, 0, stream>>>(hpk, wctxw, wctxb, wsc);
    wsum<<<dim3(96, 8), 256, 0, stream>>>(hpk, wsc, sent_vecs);

    // sentence input projection: xWs[pos][3072]
    gemm_split<<<2 * 24, 256, 0, stream>>>(
        sent_vecs, nullptr, sWihHi, sWihLo, sbih, xWs, 96, 3072, 2048, 0);

    // persistent sentence bi-GRU (tree-barrier domain 2)
    sent_rnn<<<128, 256, 0, stream>>>(
        sWhh, xWs, sbhh, sbi, barbuf + 1024);

    sent_scores<<<96, 256, 0, stream>>>(sbi, sctxw, sctxb, scores);
    doc_out<<<1, 256, 0, stream>>>(sbi, scores, out);
}

// Round 17
// 2195.423 us; speedup vs baseline: 1.2360x; 1.2360x over previous
//
#include <hip/hip_runtime.h>
#include <hip/hip_bf16.h>
#include <math.h>

// HAN: word bi-GRU + attention -> sentence bi-GRU + attention -> doc vector.
// R17 = revert to R15 (best measured: 2198 us total, word_rnn 1180 us).
// R16's full-breadth loads + cached hpk stores + faster spin all regressed.
// R15: XCD-locality remaps (word_rnn contiguous j-panels; gemm XCD-chunked),
// bf16-h broadcast (hb), exact packed h (hpk), tree barrier, M-rep=2 x 4 kq.

typedef __attribute__((ext_vector_type(8))) short short8;
typedef __attribute__((ext_vector_type(4))) float f32x4;
typedef __attribute__((ext_vector_type(4))) unsigned u32x4;

__device__ __forceinline__ unsigned short f2bf(float f) {
    unsigned int u = __float_as_uint(f);
    u += 0x7fff + ((u >> 16) & 1);   // RNE
    return (unsigned short)(u >> 16);
}
__device__ __forceinline__ float bf2f(unsigned short u) {
    return __uint_as_float(((unsigned int)u) << 16);
}
__device__ __forceinline__ float unpk2f(unsigned p) {   // hi in low16, lo in high16
    return __uint_as_float(p << 16) + __uint_as_float(p & 0xffff0000u);
}
__device__ __forceinline__ float sigmoidf_(float x) { return 1.f / (1.f + expf(-x)); }

__device__ __forceinline__ f32x4 mfma16(short8 a, short8 b, f32x4 c) {
    return __builtin_amdgcn_mfma_f32_16x16x32_bf16(a, b, c, 0, 0, 0);
}

// coherent (IF-direct) u32 store, relaxed
__device__ __forceinline__ void st_coh_u(unsigned* p, unsigned v) {
    __hip_atomic_store(p, v, __ATOMIC_RELAXED, __HIP_MEMORY_SCOPE_AGENT);
}
__device__ __forceinline__ void st_coh_f(float* p, float v) {
    __hip_atomic_store((unsigned*)p, __float_as_uint(v),
                       __ATOMIC_RELAXED, __HIP_MEMORY_SCOPE_AGENT);
}

// Tree barrier for a 128-block domain (8 groups of 16). Monotonic counters,
// all relaxed, no cache maintenance.
__device__ __forceinline__ void gbar_tree(unsigned* base, unsigned tau, int dblk) {
    asm volatile("s_waitcnt vmcnt(0)" ::: "memory");   // drain coherent stores
    __syncthreads();
    if (threadIdx.x == 0) {
        int g = dblk >> 4;
        unsigned* gcnt = base + g * 16;
        unsigned* root = base + 128;
        unsigned* flag = base + 144 + g * 16;
        unsigned old = __hip_atomic_fetch_add(gcnt, 1u, __ATOMIC_RELAXED, __HIP_MEMORY_SCOPE_AGENT);
        if ((old & 15u) == 15u)
            __hip_atomic_fetch_add(root, 1u, __ATOMIC_RELAXED, __HIP_MEMORY_SCOPE_AGENT);
        if ((dblk & 15) == 0) {
            unsigned target = 8u * (tau + 1u);
            while (__hip_atomic_load(root, __ATOMIC_RELAXED, __HIP_MEMORY_SCOPE_AGENT) < target)
                __builtin_amdgcn_s_sleep(2);
            __hip_atomic_store(flag, tau + 1u, __ATOMIC_RELAXED, __HIP_MEMORY_SCOPE_AGENT);
        } else {
            while (__hip_atomic_load(flag, __ATOMIC_RELAXED, __HIP_MEMORY_SCOPE_AGENT) < tau + 1u)
                __builtin_amdgcn_s_sleep(2);
        }
    }
    __syncthreads();
    asm volatile("" ::: "memory");
}

// ---------------- split f32 -> (hi,lo) bf16 ----------------
__global__ __launch_bounds__(256) void split_f32(const float* __restrict__ src,
                                                 unsigned short* __restrict__ hi,
                                                 unsigned short* __restrict__ lo, int n) {
    int i = blockIdx.x * blockDim.x + threadIdx.x;
    int stride = gridDim.x * blockDim.x;
    for (; i < n; i += stride) {
        float v = src[i];
        unsigned short h = f2bf(v);
        hi[i] = h;
        lo[i] = f2bf(v - bf2f(h));
    }
}

// ---------------- split-bf16 MFMA GEMM (NT), XCD-chunked 1D grid ------------
__global__ __launch_bounds__(256) void gemm_split(
    const float* __restrict__ A, const int* __restrict__ tokens,
    const unsigned short* __restrict__ Bhi, const unsigned short* __restrict__ Blo,
    const float* __restrict__ bias, float* __restrict__ C,
    int M, int N, int K, int tr96)
{
    __shared__ unsigned short Ah[64][40], Al[64][40];
    __shared__ unsigned short Bh[128][40], Bl[128][40];

    int t = threadIdx.x;
    int nt = N >> 7;
    int mt = gridDim.x / nt;
    int nchunk = nt >> 3;
    int b = blockIdx.x;
    int xcd = b & 7, bi_ = b >> 3;
    int m0 = (bi_ % mt) * 64;
    int n0 = (xcd * nchunk + bi_ / mt) * 128;

    int wave = t >> 6, lane = t & 63;
    int wm = wave >> 1, wn = wave & 1;
    int kg = lane >> 4, r16 = lane & 15;

    f32x4 acc[2][4];
#pragma unroll
    for (int i = 0; i < 2; i++)
#pragma unroll
        for (int j = 0; j < 4; j++)
#pragma unroll
            for (int q = 0; q < 4; q++) acc[i][j][q] = 0.f;

    int ar = t >> 2, ac8 = (t & 3) * 8;
    long arow = -1;
    if (m0 + ar < M) arow = tokens ? (long)tokens[m0 + ar] : (long)(m0 + ar);

    for (int kt = 0; kt < K; kt += 32) {
        {
            short8 hv, lv;
            if (arow >= 0) {
                const float* ap = A + arow * (long)K + kt + ac8;
                f32x4 u0 = *(const f32x4*)ap;
                f32x4 u1 = *(const f32x4*)(ap + 4);
#pragma unroll
                for (int i = 0; i < 8; i++) {
                    float x = (i < 4) ? u0[i] : u1[i - 4];
                    unsigned short hb = f2bf(x);
                    hv[i] = (short)hb;
                    lv[i] = (short)f2bf(x - bf2f(hb));
                }
            } else {
#pragma unroll
                for (int i = 0; i < 8; i++) { hv[i] = 0; lv[i] = 0; }
            }
            *(short8*)&Ah[ar][ac8] = hv;
            *(short8*)&Al[ar][ac8] = lv;
        }
#pragma unroll
        for (int i = 0; i < 2; i++) {
            int idx = t + i * 256;
            int br = idx >> 2, bc8 = (idx & 3) * 8;
            long go = (long)(n0 + br) * K + kt + bc8;
            *(short8*)&Bh[br][bc8] = *(const short8*)(Bhi + go);
            *(short8*)&Bl[br][bc8] = *(const short8*)(Blo + go);
        }
        __syncthreads();

        short8 afh[2], afl[2], bfh[4], bfl[4];
#pragma unroll
        for (int m16 = 0; m16 < 2; m16++) {
            afh[m16] = *(short8*)&Ah[wm * 32 + m16 * 16 + r16][kg * 8];
            afl[m16] = *(short8*)&Al[wm * 32 + m16 * 16 + r16][kg * 8];
        }
#pragma unroll
        for (int n16 = 0; n16 < 4; n16++) {
            bfh[n16] = *(short8*)&Bh[wn * 64 + n16 * 16 + r16][kg * 8];
            bfl[n16] = *(short8*)&Bl[wn * 64 + n16 * 16 + r16][kg * 8];
        }
#pragma unroll
        for (int m16 = 0; m16 < 2; m16++)
#pragma unroll
            for (int n16 = 0; n16 < 4; n16++) {
                acc[m16][n16] = mfma16(afh[m16], bfh[n16], acc[m16][n16]);
                acc[m16][n16] = mfma16(afh[m16], bfl[n16], acc[m16][n16]);
                acc[m16][n16] = mfma16(afl[m16], bfh[n16], acc[m16][n16]);
            }
        __syncthreads();
    }

#pragma unroll
    for (int m16 = 0; m16 < 2; m16++)
#pragma unroll
        for (int n16 = 0; n16 < 4; n16++)
#pragma unroll
            for (int q = 0; q < 4; q++) {
                int row = m0 + wm * 32 + m16 * 16 + kg * 4 + q;
                int col = n0 + wn * 64 + n16 * 16 + r16;
                if (row < M) {
                    long crow = tr96 ? (long)((row % 96) * 96 + row / 96) : (long)row;
                    C[crow * N + col] = acc[m16][n16][q] + bias[col];
                }
            }
}

// ---------------- persistent word bi-GRU v11 (XCD-contiguous j-panels) ------
// 256 blocks x 768 thr (12 waves = 3 m-tiles(M-rep2) x 4 K-quarters).
// j-slice remap: same-XCD blocks (blk%8) own contiguous 128-j panels.
__global__ __launch_bounds__(768) void word_rnn(
    const unsigned short* __restrict__ Whi, const unsigned short* __restrict__ Wlo,
    const float* __restrict__ xWt,   // [96 pos][96 s][3072]
    const float* __restrict__ bhh, unsigned* __restrict__ hpk,
    unsigned short* __restrict__ hb, unsigned* barbase)
{
    __shared__ unsigned short Wh[2][128][25][8];    // 102.4 KB
    __shared__ float psum[3][3][64][2][9];          // 41.5 KB

    int t = threadIdx.x;
    int blk = blockIdx.x;
    int msplit = blk >> 7;
    int dblk = blk & 127;
    unsigned* dom = barbase + msplit * 512;
    // XCD-contiguous j-panel: XCD c (blk%8) owns j [c*128, c*128+128)
    int j0 = (((dblk & 7) << 4) + (dblk >> 3)) << 3;
    int wv = t >> 6;                  // 0..11
    int w3 = wv % 3, kq = wv / 3;     // m-tile (32 rows), K-quarter (0..3)
    int lane = t & 63, kg4 = lane >> 4, r16 = lane & 15;
    int wstart = blk & 7;             // per-block window rotation (8 windows)

    for (int i = t; i < 4096; i += 768) {
        int kg = i >> 5, br = i & 31;
        if (br < 24) {
            long src = (long)((br >> 3) * 1024 + j0 + (br & 7)) * 1024 + kg * 8;
            *(short8*)&Wh[0][kg][br][0] = *(const short8*)(Whi + src);
            *(short8*)&Wh[1][kg][br][0] = *(const short8*)(Wlo + src);
        }
    }
    __syncthreads();

    int jj = r16 & 7;
    int j = j0 + jj;
    float b_r = bhh[j], b_z = bhh[1024 + j], b_n = bhh[2048 + j];
    int sf0 = w3 * 32 + r16;          // row rep 0 (rep 1 = +16)
    const long ROWSTRIDE = (long)16 * 96 * 2048;   // 16 sentences

    short8 X0, X1, X2, X3, Y0, Y1, Y2, Y3;

#define KOFF(i) (kq * 8 + ((wstart + (i)) & 7))

#define LDW2(s, i)                                                        \
    do {                                                                  \
        X##s = *(const short8*)(ab0 + KOFF(i) * 32);                      \
        Y##s = *(const short8*)(ab1 + KOFF(i) * 32);                      \
    } while (0)

#define DOW2(s, i)                                                        \
    do {                                                                  \
        int kgB = KOFF(i) * 4 + kg4;                                      \
        short8 b0h = *(short8*)&Wh[0][kgB][r16][0];                       \
        short8 b0l = *(short8*)&Wh[1][kgB][r16][0];                       \
        short8 b1h = *(short8*)&Wh[0][kgB][16 + jj][0];                   \
        short8 b1l = *(short8*)&Wh[1][kgB][16 + jj][0];                   \
        acc00 = mfma16(X##s, b0h, acc00);                                 \
        acc10 = mfma16(Y##s, b0h, acc10);                                 \
        acc00 = mfma16(X##s, b0l, acc00);                                 \
        acc10 = mfma16(Y##s, b0l, acc10);                                 \
        acc01 = mfma16(X##s, b1h, acc01);                                 \
        acc11 = mfma16(Y##s, b1h, acc11);                                 \
        acc01 = mfma16(X##s, b1l, acc01);                                 \
        acc11 = mfma16(Y##s, b1l, acc11);                                 \
    } while (0)

    for (int tau = 0; tau < 96; tau++) {
        int pos  = msplit ? (95 - tau) : tau;
        int posp = msplit ? (96 - tau) : (tau - 1);

        const unsigned short* ab0 = hb + ((long)sf0 * 96 + posp) * 2048 + msplit * 1024 + kg4 * 8;
        const unsigned short* ab1 = ab0 + ROWSTRIDE;

        f32x4 acc00, acc01, acc10, acc11;
#pragma unroll
        for (int q = 0; q < 4; q++) { acc00[q] = 0.f; acc01[q] = 0.f; acc10[q] = 0.f; acc11[q] = 0.f; }

        // epilogue operands (kq==0 producing lanes), retire under K-loop
        float xwv[2][4][3];
        float hpv[2][4];
#pragma unroll
        for (int mi = 0; mi < 2; mi++)
#pragma unroll
            for (int q = 0; q < 4; q++) {
                if (kq == 0 && r16 < 8) {
                    int hloc = w3 * 32 + mi * 16 + kg4 * 4 + q;
                    const float* xp = xWt + ((long)pos * 96 + hloc) * 3072 + j;
                    xwv[mi][q][0] = xp[0];
                    xwv[mi][q][1] = xp[1024];
                    xwv[mi][q][2] = xp[2048];
                    hpv[mi][q] = (tau > 0)
                        ? unpk2f(hpk[((long)hloc * 96 + posp) * 2048 + msplit * 1024 + j]) : 0.f;
                } else {
                    xwv[mi][q][0] = xwv[mi][q][1] = xwv[mi][q][2] = 0.f;
                    hpv[mi][q] = 0.f;
                }
            }

        if (tau > 0) {
            LDW2(0, 0); LDW2(1, 1); LDW2(2, 2); LDW2(3, 3);
            DOW2(0, 0);  LDW2(0, 4);
            DOW2(1, 1);  LDW2(1, 5);
            DOW2(2, 2);  LDW2(2, 6);
            DOW2(3, 3);  LDW2(3, 7);
            DOW2(0, 4);
            DOW2(1, 5);
            DOW2(2, 6);
            DOW2(3, 7);
        }

        // K-quarter partial exchange (kq 1..3 write, kq 0 reduces)
        if (kq >= 1) {
#pragma unroll
            for (int q = 0; q < 4; q++) {
                psum[kq - 1][w3][lane][0][q]     = acc00[q];
                psum[kq - 1][w3][lane][0][4 + q] = acc01[q];
                psum[kq - 1][w3][lane][1][q]     = acc10[q];
                psum[kq - 1][w3][lane][1][4 + q] = acc11[q];
            }
        }
        __syncthreads();

        if (kq == 0) {
#pragma unroll
            for (int mi = 0; mi < 2; mi++) {
#pragma unroll
                for (int q = 0; q < 4; q++) {
                    float a0 = (mi == 0) ? acc00[q] : acc10[q];
                    float a1 = (mi == 0) ? acc01[q] : acc11[q];
                    float g0 = a0 + psum[0][w3][lane][mi][q]
                                  + psum[1][w3][lane][mi][q]
                                  + psum[2][w3][lane][mi][q];
                    float g2 = a1 + psum[0][w3][lane][mi][4 + q]
                                  + psum[1][w3][lane][mi][4 + q]
                                  + psum[2][w3][lane][mi][4 + q];
                    float g1 = __shfl_xor(g0, 8);
                    float rr = sigmoidf_(xwv[mi][q][0] + g0 + b_r);
                    float zz = sigmoidf_(xwv[mi][q][1] + g1 + b_z);
                    float nn = tanhf(xwv[mi][q][2] + rr * (g2 + b_n));
                    float hnew = (1.f - zz) * nn + zz * hpv[mi][q];
                    unsigned hbb = f2bf(hnew);
                    unsigned nb = (unsigned)__shfl_xor((int)hbb, 1);
                    if (r16 < 8) {
                        int hloc = w3 * 32 + mi * 16 + kg4 * 4 + q;
                        long base = ((long)hloc * 96 + pos) * 2048 + msplit * 1024 + j;
                        unsigned lb = f2bf(hnew - bf2f((unsigned short)hbb));
                        st_coh_u(hpk + base, hbb | (lb << 16));
                        if ((jj & 1) == 0)
                            st_coh_u((unsigned*)hb + (base >> 1), hbb | (nb << 16));
                    }
                }
            }
        }

        if (tau != 95) gbar_tree(dom, tau, dblk);
    }
#undef KOFF
#undef LDW2
#undef DOW2
}

// ---------------- word attention (read exact hpk) ----------------
__global__ __launch_bounds__(256) void wscore(
    const unsigned* __restrict__ hpk, const float* __restrict__ wctx,
    const float* __restrict__ wctx_b, float* __restrict__ wsc)
{
    int tok = blockIdx.x * 4 + (threadIdx.x >> 6);
    int lane = threadIdx.x & 63;
    const unsigned* row = hpk + (long)tok * 2048 + lane * 32;
    const float* cp = wctx + lane * 32;
    float p = 0.f;
#pragma unroll
    for (int i = 0; i < 32; i += 4) {
        u32x4 v = *(const u32x4*)(row + i);
        f32x4 c = *(const f32x4*)(cp + i);
        p += unpk2f(v[0]) * c[0] + unpk2f(v[1]) * c[1]
           + unpk2f(v[2]) * c[2] + unpk2f(v[3]) * c[3];
    }
    p += __shfl_xor(p, 32); p += __shfl_xor(p, 16); p += __shfl_xor(p, 8);
    p += __shfl_xor(p, 4);  p += __shfl_xor(p, 2);  p += __shfl_xor(p, 1);
    if (lane == 0) wsc[tok] = expf(p + wctx_b[0]);
}

__global__ __launch_bounds__(256) void wsum(
    const unsigned* __restrict__ hpk, const float* __restrict__ wsc,
    float* __restrict__ sent_vecs)
{
    int s = blockIdx.x;
    int c = blockIdx.y * 256 + threadIdx.x;
    float acc = 0.f;
    for (int tk = 0; tk < 96; tk++)
        acc += wsc[s * 96 + tk] * unpk2f(hpk[((long)s * 96 + tk) * 2048 + c]);
    sent_vecs[(long)s * 2048 + c] = acc;
}

// ---------------- persistent sentence bi-GRU (tree barrier) ----------------
__global__ __launch_bounds__(256) void sent_rnn(
    const float* __restrict__ sWhh, const float* __restrict__ xWs,
    const float* __restrict__ sbhh, float* __restrict__ sbi,
    unsigned* barbase)
{
    __shared__ float Wl[24 * 1028];
    __shared__ float hsh[2048];
    __shared__ float part[4][48];

    int t = threadIdx.x;
    int j0 = blockIdx.x * 8;
    int w = t >> 6, lane = t & 63;

    for (int i = t; i < 24 * 1024; i += 256) {
        int row = i >> 10, k = i & 1023;
        Wl[row * 1028 + k] = sWhh[(long)((row >> 3) * 1024 + j0 + (row & 7)) * 1024 + k];
    }

    for (int tau = 0; tau < 96; tau++) {
        int posp0 = tau - 1, posp1 = 96 - tau;
        __syncthreads();
        for (int i = t; i < 2048; i += 256) {
            int bq = i >> 10, k = i & 1023;
            int pp = bq ? posp1 : posp0;
            hsh[i] = (tau > 0) ? sbi[(long)pp * 2048 + bq * 1024 + k] : 0.f;
        }
        __syncthreads();

        if (lane < 48) {
            int row = lane >> 1, bq = lane & 1;
            const float* wp = &Wl[row * 1028 + w * 256];
            const float* hp = &hsh[bq * 1024 + w * 256];
            float accd = 0.f;
            for (int k = 0; k < 256; k += 4) {
                f32x4 wv = *(const f32x4*)(wp + k);
                f32x4 hv = *(const f32x4*)(hp + k);
                accd += wv[0] * hv[0] + wv[1] * hv[1] + wv[2] * hv[2] + wv[3] * hv[3];
            }
            part[w][lane] = accd;
        }
        __syncthreads();

        if (t < 16) {
            int jl2 = t >> 1, bq = t & 1;
            int jv = j0 + jl2;
            int pos = bq ? (95 - tau) : tau;
            int pp  = bq ? posp1 : posp0;
            const float* xp = xWs + (long)pos * 3072;
            int d0 = (0 * 8 + jl2) * 2 + bq;
            int d1 = (1 * 8 + jl2) * 2 + bq;
            int d2 = (2 * 8 + jl2) * 2 + bq;
            float D0 = part[0][d0] + part[1][d0] + part[2][d0] + part[3][d0];
            float D1 = part[0][d1] + part[1][d1] + part[2][d1] + part[3][d1];
            float D2 = part[0][d2] + part[1][d2] + part[2][d2] + part[3][d2];
            float rr = sigmoidf_(xp[jv] + D0 + sbhh[jv]);
            float zz = sigmoidf_(xp[1024 + jv] + D1 + sbhh[1024 + jv]);
            float nn = tanhf(xp[2048 + jv] + rr * (D2 + sbhh[2048 + jv]));
            float hprev = (tau > 0) ? sbi[(long)pp * 2048 + bq * 1024 + jv] : 0.f;
            float hnew = (1.f - zz) * nn + zz * hprev;
            st_coh_f(sbi + (long)pos * 2048 + bq * 1024 + jv, hnew);
        }

        if (tau != 95) gbar_tree(barbase, tau, blockIdx.x);
    }
}

// ---------------- sentence attention ----------------
__global__ __launch_bounds__(256) void sent_scores(
    const float* __restrict__ sbi, const float* __restrict__ sctx,
    const float* __restrict__ sctx_b, float* __restrict__ scores)
{
    __shared__ float red[4];
    int s = blockIdx.x, t = threadIdx.x, c = t * 8;
    const float* row = sbi + (long)s * 2048 + c;
    float p = 0.f;
#pragma unroll
    for (int i = 0; i < 8; i++) p += row[i] * sctx[c + i];
    p += __shfl_xor(p, 32); p += __shfl_xor(p, 16); p += __shfl_xor(p, 8);
    p += __shfl_xor(p, 4);  p += __shfl_xor(p, 2);  p += __shfl_xor(p, 1);
    int lane = t & 63, w = t >> 6;
    if (lane == 0) red[w] = p;
    __syncthreads();
    if (t == 0) scores[s] = expf(red[0] + red[1] + red[2] + red[3] + sctx_b[0]);
}

__global__ __launch_bounds__(256) void doc_out(
    const float* __restrict__ sbi, const float* __restrict__ scores,
    float* __restrict__ out)
{
    int t = threadIdx.x, c = t * 8;
    float acc[8];
#pragma unroll
    for (int i = 0; i < 8; i++) acc[i] = 0.f;
    for (int s = 0; s < 96; s++) {
        float sc = scores[s];
        const float* row = sbi + (long)s * 2048 + c;
#pragma unroll
        for (int i = 0; i < 8; i++) acc[i] += sc * row[i];
    }
#pragma unroll
    for (int i = 0; i < 8; i++) out[c + i] = acc[i];
}

// ---------------- host ----------------
extern "C" void kernel_launch(void* const* d_in, const int* in_sizes, int n_in,
                              void* d_out, int out_size, void* d_ws, size_t ws_size,
                              hipStream_t stream)
{
    const int*   tokens    = (const int*)  d_in[0];
    const float* embedding = (const float*)d_in[1];
    const float* wWih = (const float*)d_in[2];
    const float* wWhh = (const float*)d_in[3];
    const float* wbih = (const float*)d_in[4];
    const float* wbhh = (const float*)d_in[5];
    const float* sWih = (const float*)d_in[6];
    const float* sWhh = (const float*)d_in[7];
    const float* sbih = (const float*)d_in[8];
    const float* sbhh = (const float*)d_in[9];
    const float* wctxw = (const float*)d_in[10];
    const float* wctxb = (const float*)d_in[11];
    const float* sctxw = (const float*)d_in[12];
    const float* sctxb = (const float*)d_in[13];
    float* out = (float*)d_out;

    char* p = (char*)d_ws;
    auto alloc = [&](size_t bytes) -> char* {
        char* r = p;
        p += (bytes + 255) & ~(size_t)255;
        return r;
    };
    unsigned short* WihHi  = (unsigned short*)alloc(3072l * 1024 * 2);
    unsigned short* WihLo  = (unsigned short*)alloc(3072l * 1024 * 2);
    unsigned short* WhhHi  = (unsigned short*)alloc(3072l * 1024 * 2);
    unsigned short* WhhLo  = (unsigned short*)alloc(3072l * 1024 * 2);
    unsigned short* sWihHi = (unsigned short*)alloc(3072l * 2048 * 2);
    unsigned short* sWihLo = (unsigned short*)alloc(3072l * 2048 * 2);
    float* xWt       = (float*)alloc(9216l * 3072 * 4);     // [pos][s][3072]
    unsigned* hpk    = (unsigned*)alloc(9216l * 2048 * 4);  // packed exact h / bi
    unsigned short* hb = (unsigned short*)alloc(9216l * 2048 * 2);  // bf16 h
    float* sent_vecs = (float*)alloc(96l * 2048 * 4);
    float* xWs       = (float*)alloc(96l * 3072 * 4);
    float* sbi       = (float*)alloc(96l * 2048 * 4);       // also sent h state
    float* scores    = (float*)alloc(512);
    float* wsc       = (float*)alloc(9216l * 4);
    unsigned* barbuf = (unsigned*)alloc(16384);
    (void)ws_size; (void)in_sizes; (void)n_in; (void)out_size;

    hipMemsetAsync(barbuf, 0, 16384, stream);

    split_f32<<<1024, 256, 0, stream>>>(wWih, WihHi, WihLo, 3072 * 1024);
    split_f32<<<1024, 256, 0, stream>>>(wWhh, WhhHi, WhhLo, 3072 * 1024);
    split_f32<<<1024, 256, 0, stream>>>(sWih, sWihHi, sWihLo, 3072 * 2048);

    // word input projection, stored transposed: xWt[pos][s][3072]
    gemm_split<<<144 * 24, 256, 0, stream>>>(
        embedding, tokens, WihHi, WihLo, wbih, xWt, 9216, 3072, 1024, 1);

    // persistent word bi-GRU (fwd/bwd tree-barrier domains 0,1)
    word_rnn<<<256, 768, 0, stream>>>(
        WhhHi, WhhLo, xWt, wbhh, hpk, hb, barbuf);

    // word attention
    wscore<<<2304, 256, 0, stream>>>(hpk, wctxw, wctxb, wsc);
    wsum<<<dim3(96, 8), 256, 0, stream>>>(hpk, wsc, sent_vecs);

    // sentence input projection: xWs[pos][3072]
    gemm_split<<<2 * 24, 256, 0, stream>>>(
        sent_vecs, nullptr, sWihHi, sWihLo, sbih, xWs, 96, 3072, 2048, 0);

    // persistent sentence bi-GRU (tree-barrier domain 2)
    sent_rnn<<<128, 256, 0, stream>>>(
        sWhh, xWs, sbhh, sbi, barbuf + 1024);

    sent_scores<<<96, 256, 0, stream>>>(sbi, sctxw, sctxb, scores);
    doc_out<<<1, 256, 0, stream>>>(sbi, scores, out);
}